// Round 10
// baseline (171.747 us; speedup 1.0000x reference)
//
#include <hip/hip_runtime.h>
#include <hip/hip_bf16.h>
#include <math.h>

#define HEADS 16
#define KV_HEADS 8
#define DIMS 64
#define IN_DIMS 1024
#define BATCH 2
#define SEQ 2048

typedef __attribute__((ext_vector_type(8))) short short8;   // 8 bf16 (4 VGPRs)
typedef __attribute__((ext_vector_type(4))) float f32x4;    // MFMA accumulator
typedef __attribute__((ext_vector_type(4))) unsigned int u32x4;

__device__ __forceinline__ short f2bf(float f) {
    __hip_bfloat16 h = __float2bfloat16(f);
    return *reinterpret_cast<short*>(&h);
}

// Raw v_exp_f32 (exp2) -- r18-verified (libm exp2f carries range handling).
__device__ __forceinline__ float e2(float x) {
    return __builtin_amdgcn_exp2f(x);
}

// gfx950 packed f32->bf16.  m240: keep OUT of hot compute loops (r16: -4%);
// fine in memory-bound prep kernels.
__device__ __forceinline__ unsigned int cvtpk(float a, float b) {
    unsigned int r;
    asm("v_cvt_pk_bf16_f32 %0, %1, %2" : "=v"(r) : "v"(a), "v"(b));
    return r;
}

// Direct global->LDS async copy, 16B per lane (m97 pattern).
__device__ __forceinline__ void gl_lds16(const void* g, void* l) {
    __builtin_amdgcn_global_load_lds(
        (const __attribute__((address_space(1))) unsigned int*)g,
        (__attribute__((address_space(3))) unsigned int*)l, 16, 0, 0);
}

#define LOG2_10000 13.287712379549449f
#define LOG2_2PI   2.6514961294723187f
#define CSCALE (0.5f * 1.4426950408889634f)   // attn scale * log2(e)

// Revolution-space sin/cos (r18-verified): v_sin/v_cos compute sin(x*2pi);
// fract() is the exact periodic reduction.  Angle err ~1e-4 rad << bf16 lsb.
__device__ __forceinline__ void sincos_rev(float ang_rev, float* sn, float* cs) {
    float fr = ang_rev - floorf(ang_rev);
    *sn = __builtin_amdgcn_sinf(fr);
    *cs = __builtin_amdgcn_cosf(fr);
}

// ---------------------------------------------------------------------------
// All weight prep + activation cvt in ONE launch (z-indexed).
//  z=0: WT[0:1024] = Wq^T   z=1: WT[1024:1536] = Wk^T   z=2: WT[1536:2048] = Wv^T
//  z=3: WoPt[n][d] = bf16(Wo[2d][n] + Wo[2d+1][n])
//  z=4,5: Abf = bf16(q)
// ---------------------------------------------------------------------------
__global__ __launch_bounds__(256) void prep_weights(
    const float* __restrict__ Wq, const float* __restrict__ Wk,
    const float* __restrict__ Wv, const float* __restrict__ Wo,
    short* __restrict__ WT, short* __restrict__ WoPt,
    const float* __restrict__ qin, short* __restrict__ Abf)
{
    __shared__ float t[32][33];
    int z = blockIdx.z;
    if (z >= 4) {
        int i = (z - 4) * 1024 + blockIdx.y * 32 + blockIdx.x;
        size_t idx = ((size_t)i * 256 + threadIdx.x) * 8;
        float4 a = *(const float4*)(qin + idx);
        float4 c = *(const float4*)(qin + idx + 4);
        u32x4 s = { cvtpk(a.x, a.y), cvtpk(a.z, a.w),
                    cvtpk(c.x, c.y), cvtpk(c.z, c.w) };
        *(u32x4*)(Abf + idx) = s;
        return;
    }
    int bx = blockIdx.x * 32, by = blockIdx.y * 32;
    int x = threadIdx.x & 31, y = threadIdx.x >> 5;
    if (z == 3) {
        if (by >= 512) return;
        #pragma unroll
        for (int i = 0; i < 32; i += 8) {
            int d = by + y + i;
            t[y + i][x] = Wo[(size_t)(2 * d) * 1024 + bx + x]
                        + Wo[(size_t)(2 * d + 1) * 1024 + bx + x];
        }
        __syncthreads();
        #pragma unroll
        for (int i = 0; i < 32; i += 8)
            WoPt[(size_t)(bx + y + i) * 512 + by + x] = f2bf(t[x][y + i]);
    } else {
        const float* W = (z == 0) ? Wq : ((z == 1) ? Wk : Wv);
        int N = (z == 0) ? 1024 : 512;
        if (bx >= N) return;
        short* dst = WT + ((z == 0) ? 0 : ((z == 1) ? (size_t)1024 * 1024
                                                    : (size_t)1536 * 1024));
        #pragma unroll
        for (int i = 0; i < 32; i += 8)
            t[y + i][x] = W[(size_t)(by + y + i) * N + bx + x];
        __syncthreads();
        #pragma unroll
        for (int i = 0; i < 32; i += 8)
            dst[(size_t)(bx + y + i) * 1024 + by + x] = f2bf(t[x][y + i]);
    }
}

// ---------------------------------------------------------------------------
// gemm_qkv (r19): QKV projection with FUSED rope/transpose epilogue.
// Main loop identical to r18's gemm_af32 (BM=BN=128, BK=64, 4 waves,
// global_load_lds staging).  XQKV is ELIMINATED: the epilogue applies the
// prep_qkv transforms in-register and writes Qp/Kb/Vtg directly (saves
// 33.6MB f32 write + 33.6MB read + one launch).  Region is block-uniform:
// col0<1024 -> Q-rope+pairsum; col0<1536 -> K-rope; else V-transpose.
// Q/K pair (2i,2i+1) sits in adjacent lanes (col parity == lane parity) ->
// one shfl_xor(1) exchange; even lanes store.  V: acc[i][j]'s 4 r-values
// are 4 consecutive keys at one dim -> short4 store IS the transpose.
// Same f32 math as r18's prep_qkv -> bit-identical numerics.
// ---------------------------------------------------------------------------
__global__ __launch_bounds__(256) void gemm_qkv(
    const short* __restrict__ A, const short* __restrict__ Bt,
    short* __restrict__ Qp, short* __restrict__ Kb, short* __restrict__ Vtg)
{
    const int K = 1024;
    __shared__ short As[128][64];
    __shared__ short Bs[128][64];

    int tid  = threadIdx.x;
    int lane = tid & 63, wave = tid >> 6;
    int quad = lane >> 4, ln = lane & 15;
    int wm = (wave >> 1) * 64, wn = (wave & 1) * 64;
    int row0 = blockIdx.y * 128, col0 = blockIdx.x * 128;

    int sr = lane >> 3;              // staging row within 8-row group
    int sk = (lane & 7) * 8;         // staging col (shorts)

    f32x4 acc[4][4] = {};

    for (int kt = 0; kt < K; kt += 64) {
        #pragma unroll
        for (int u = 0; u < 4; ++u) {
            int r = wave * 32 + u * 8;
            gl_lds16(A + (size_t)(row0 + r + sr) * K + kt + sk, &As[r][0]);
        }
        #pragma unroll
        for (int u = 0; u < 4; ++u) {
            int r = wave * 32 + u * 8;
            gl_lds16(Bt + (size_t)(col0 + r + sr) * K + kt + sk, &Bs[r][0]);
        }
        __syncthreads();

        #pragma unroll
        for (int k0 = 0; k0 < 64; k0 += 32) {
            short8 af[4], bfr[4];
            #pragma unroll
            for (int i = 0; i < 4; ++i)
                af[i] = *(const short8*)&As[wm + 16 * i + ln][k0 + quad * 8];
            #pragma unroll
            for (int j = 0; j < 4; ++j)
                bfr[j] = *(const short8*)&Bs[wn + 16 * j + ln][k0 + quad * 8];
            #pragma unroll
            for (int i = 0; i < 4; ++i)
                #pragma unroll
                for (int j = 0; j < 4; ++j)
                    acc[i][j] = __builtin_amdgcn_mfma_f32_16x16x32_bf16(
                        af[i], bfr[j], acc[i][j], 0, 0, 0);
        }
        __syncthreads();
    }

    // ----- fused epilogue -----
    bool evn = (lane & 1) == 0;

    if (col0 < 1024) {
        // Q: rope + pairsum + scale -> Qp[row][col/2] (even lanes store)
        #pragma unroll
        for (int j = 0; j < 4; ++j) {
            int col = col0 + wn + 16 * j + ln;
            float tr = e2(-(float)(col & ~1) / 1024.f * LOG2_10000 - LOG2_2PI);
            #pragma unroll
            for (int i = 0; i < 4; ++i)
                #pragma unroll
                for (int r = 0; r < 4; ++r) {
                    int row = row0 + wm + 16 * i + quad * 4 + r;
                    float xe = acc[i][j][r];
                    float xo = __shfl_xor(xe, 1);
                    float sn, cs;
                    sincos_rev((float)((row & (SEQ - 1)) + 1) * tr, &sn, &cs);
                    float o = (xe * (cs + sn) + xo * (cs - sn)) * CSCALE;
                    if (evn)
                        Qp[(size_t)row * 512 + (col >> 1)] = f2bf(o);
                }
        }
    } else if (col0 < 1536) {
        // K: rope -> Kb[row][{2i,2i+1}] as one u32 (even lanes store)
        #pragma unroll
        for (int j = 0; j < 4; ++j) {
            int c = col0 + wn + 16 * j + ln - 1024;
            float tr = e2(-(float)(c & ~1) / 512.f * LOG2_10000 - LOG2_2PI);
            #pragma unroll
            for (int i = 0; i < 4; ++i)
                #pragma unroll
                for (int r = 0; r < 4; ++r) {
                    int row = row0 + wm + 16 * i + quad * 4 + r;
                    float xe = acc[i][j][r];
                    float xo = __shfl_xor(xe, 1);
                    float sn, cs;
                    sincos_rev((float)((row & (SEQ - 1)) + 1) * tr, &sn, &cs);
                    unsigned int o = cvtpk(xe * cs - xo * sn, xe * sn + xo * cs);
                    if (evn)
                        *(unsigned int*)(Kb + (size_t)row * 512 + c) = o;
                }
        }
    } else {
        // V: transposed bf16 store -> Vtg[b][dim][key] (short4 = 4 keys)
        int b = row0 >> 11;
        int s0 = (row0 & (SEQ - 1)) + wm + quad * 4;
        #pragma unroll
        for (int j = 0; j < 4; ++j) {
            int dim = col0 + wn + 16 * j + ln - 1536;
            short* dst = Vtg + ((size_t)(b * 512 + dim)) * SEQ + s0;
            #pragma unroll
            for (int i = 0; i < 4; ++i) {
                short4 o4 = { f2bf(acc[i][j][0]), f2bf(acc[i][j][1]),
                              f2bf(acc[i][j][2]), f2bf(acc[i][j][3]) };
                *(short4*)(dst + 16 * i) = o4;
            }
        }
    }
}

// ---------------------------------------------------------------------------
// MFMA flash attention (r18-verified, UNCHANGED).  8-wave QBLK=128;
// K/V staging split by wave-group; 1 global load + 1 ds_write per thread
// per tile; 1 barrier/tile; raw v_exp_f32 softmax.
//
// ZERO-LDS softmax path (both MFMAs operand-swapped):
//   QK^T:  sc = mfma(Kfrag, Qfrag)  -> lane (quad,ln) holds S[key][q=qw+ln]
//   PV^T:  O^T = mfma(Vfrag, Pfrag) <- P packed in-register as B-fragments
// K rows stored pi-PERMUTED in LDS (key[k5 k4 k3 k2 k1 k0] ->
// row[k5 k2 k4 k3 k1 k0]) so sc lands exactly in PV-B arrangement:
//   sc[j0][r] = S[key = 32*(j0>>1) + 8*quad + 4*(j0&1) + r][q]
// LDS: Qs[128][40] + Ks[2][64][40] + Vt[2][32][72] = 29.7 KB.
// ---------------------------------------------------------------------------
__global__ __launch_bounds__(512) void flash_attn(
    const short* __restrict__ Qp, const short* __restrict__ Kb,
    const short* __restrict__ Vtg, short* __restrict__ AO32)
{
    __shared__ short Qs[128][40];
    __shared__ short Ks[2][64][40];
    __shared__ short Vt[2][32][72];

    int tid = threadIdx.x;                // 0..511
    int qt = blockIdx.x & 15;             // SEQ/128 q-tiles
    int h  = (blockIdx.x >> 4) & 15;
    int b  = blockIdx.x >> 8;

    int lane = tid & 63, wave = tid >> 6; // 8 waves
    int quad = lane >> 4, ln = lane & 15;
    int qw = wave * 16;

    // Stage Q tile: 128 rows x 32 bf16 (1 short8/thread, 512 threads)
    {
        int row = tid >> 2, off = (tid & 3) * 8;
        *(short8*)&Qs[row][off] =
            *(const short8*)(Qp + (size_t)(b * SEQ + qt * 128 + row) * 512 + h * 32 + off);
    }

    const short* Kgb = Kb + (size_t)(b * SEQ) * 512 + 32 * h;
    const short* Vgb = Vtg + ((size_t)b * 512 + 32 * h) * SEQ;

    // Staging roles: waves 0-3 stage K (pi-permuted rows), waves 4-7 stage V.
    bool doK = tid < 256;
    int st = tid & 255;
    int krow = st >> 2, koff = (st & 3) * 8;      // K: 64 keys x 32 bf16
    int prow = ((krow >> 5) << 5) | (((krow >> 2) & 1) << 4)
             | (((krow >> 3) & 3) << 2) | (krow & 3);
    int vrow = st >> 3, voff = (st & 7) * 8;      // V: 32 dims x 64 keys

    // Prologue: stage tile 0 into buffer 0 (wave-uniform branch)
    short8 sreg;
    if (doK) {
        sreg = *(const short8*)(Kgb + (size_t)krow * 512 + koff);
        *(short8*)&Ks[0][prow][koff] = sreg;
    } else {
        sreg = *(const short8*)(Vgb + (size_t)vrow * SEQ + voff);
        *(short8*)&Vt[0][vrow][voff] = sreg;
    }
    __syncthreads();

    short8 af = *(const short8*)&Qs[qw + ln][quad * 8];   // loop-invariant

    float lsum = 0.f;                   // softmax denom partial, query qw+ln
    f32x4 Oacc[2] = {};
    const f32x4 zz = {};                // hoisted zero accumulator regs

    for (int t = 0; t < 32; ++t) {
        int cur = t & 1;

        // Issue next-tile global load early (hides under compute)
        if (t < 31) {
            int ktn = (t + 1) * 64;
            if (doK)
                sreg = *(const short8*)(Kgb + (size_t)(ktn + krow) * 512 + koff);
            else
                sreg = *(const short8*)(Vgb + (size_t)vrow * SEQ + ktn + voff);
        }

        // Swapped QK^T on pi-permuted K rows:
        // sc[j0][r] = S[key = 32*(j0>>1) + 8*quad + 4*(j0&1) + r][q=qw+ln]
        f32x4 sc[4];
        __builtin_amdgcn_s_setprio(1);
        #pragma unroll
        for (int j0 = 0; j0 < 4; ++j0) {
            short8 kf = *(const short8*)&Ks[cur][j0 * 16 + ln][quad * 8];
            sc[j0] = __builtin_amdgcn_mfma_f32_16x16x32_bf16(kf, af, zz, 0, 0, 0);
        }
        __builtin_amdgcn_s_setprio(0);

        // No-max softmax numerators via raw v_exp_f32, packed IN-REGISTER
        // as PV B-fragments (f2bf per m240).
        short8 pf[2];
        #pragma unroll
        for (int kg = 0; kg < 2; ++kg) {
            float p0 = e2(sc[2 * kg][0]);
            float p1 = e2(sc[2 * kg][1]);
            float p2 = e2(sc[2 * kg][2]);
            float p3 = e2(sc[2 * kg][3]);
            float p4 = e2(sc[2 * kg + 1][0]);
            float p5 = e2(sc[2 * kg + 1][1]);
            float p6 = e2(sc[2 * kg + 1][2]);
            float p7 = e2(sc[2 * kg + 1][3]);
            lsum += ((p0 + p1) + (p2 + p3)) + ((p4 + p5) + (p6 + p7));
            short8 s = { f2bf(p0), f2bf(p1), f2bf(p2), f2bf(p3),
                         f2bf(p4), f2bf(p5), f2bf(p6), f2bf(p7) };
            pf[kg] = s;
        }

        // Swapped PV: Oacc[ng] = O^T tile, A = V^T fragment, B = pf (regs).
        __builtin_amdgcn_s_setprio(1);
        #pragma unroll
        for (int kg = 0; kg < 2; ++kg) {
            #pragma unroll
            for (int ng = 0; ng < 2; ++ng) {
                short8 vf = *(const short8*)&Vt[cur][ng * 16 + ln][kg * 32 + quad * 8];
                Oacc[ng] = __builtin_amdgcn_mfma_f32_16x16x32_bf16(
                    vf, pf[kg], Oacc[ng], 0, 0, 0);
            }
        }
        __builtin_amdgcn_s_setprio(0);

        // Write next tile into the other buffer (read side drained by the
        // barrier at the end of the PREVIOUS iteration).
        if (t < 31) {
            if (doK) *(short8*)&Ks[cur ^ 1][prow][koff] = sreg;
            else     *(short8*)&Vt[cur ^ 1][vrow][voff] = sreg;
        }
        __syncthreads();
    }

    // Denominator: quads hold disjoint key subsets of the SAME query qw+ln
    lsum += __shfl_xor(lsum, 16);
    lsum += __shfl_xor(lsum, 32);
    float inv = 1.f / lsum;

    // Epilogue: lane (quad,ln) holds O^T[d = ng*16 + quad*4 + r][q = qw+ln]
    size_t row = (size_t)(b * SEQ) + qt * 128 + qw + ln;
    #pragma unroll
    for (int ng = 0; ng < 2; ++ng) {
        short4 o4 = { f2bf(Oacc[ng][0] * inv), f2bf(Oacc[ng][1] * inv),
                      f2bf(Oacc[ng][2] * inv), f2bf(Oacc[ng][3] * inv) };
        *(short4*)&AO32[row * 512 + h * 32 + ng * 16 + quad * 4] = o4;
    }
}

// ---------------------------------------------------------------------------
// Output GEMM: out[4096][1024] = AO32[4096][512] @ WoPt[1024][512]^T.
// BM=64, BN=128; global_load_lds staging, linear LDS (r13).
// ---------------------------------------------------------------------------
__global__ __launch_bounds__(256) void gemm_wo(
    const short* __restrict__ A, const short* __restrict__ Bt,
    float* __restrict__ C)
{
    __shared__ short As[64][64];
    __shared__ short Bs[128][64];

    int tid  = threadIdx.x;
    int lane = tid & 63, wave = tid >> 6;
    int quad = lane >> 4, ln = lane & 15;
    int wm = (wave >> 1) * 32, wn = (wave & 1) * 64;
    int row0 = blockIdx.y * 64, col0 = blockIdx.x * 128;
    const int K = 512, N = 1024;

    int sr = lane >> 3;
    int sk = (lane & 7) * 8;

    f32x4 acc[2][4] = {};

    for (int kt = 0; kt < K; kt += 64) {
        #pragma unroll
        for (int u = 0; u < 2; ++u) {
            int r = wave * 16 + u * 8;
            gl_lds16(A + (size_t)(row0 + r + sr) * K + kt + sk, &As[r][0]);
        }
        #pragma unroll
        for (int u = 0; u < 4; ++u) {
            int r = wave * 32 + u * 8;
            gl_lds16(Bt + (size_t)(col0 + r + sr) * K + kt + sk, &Bs[r][0]);
        }
        __syncthreads();

        #pragma unroll
        for (int k0 = 0; k0 < 64; k0 += 32) {
            short8 af[2], bfr[4];
            #pragma unroll
            for (int i = 0; i < 2; ++i)
                af[i] = *(const short8*)&As[wm + 16 * i + ln][k0 + quad * 8];
            #pragma unroll
            for (int j = 0; j < 4; ++j)
                bfr[j] = *(const short8*)&Bs[wn + 16 * j + ln][k0 + quad * 8];
            #pragma unroll
            for (int i = 0; i < 2; ++i)
                #pragma unroll
                for (int j = 0; j < 4; ++j)
                    acc[i][j] = __builtin_amdgcn_mfma_f32_16x16x32_bf16(
                        af[i], bfr[j], acc[i][j], 0, 0, 0);
        }
        __syncthreads();
    }

    #pragma unroll
    for (int i = 0; i < 2; ++i)
        #pragma unroll
        for (int j = 0; j < 4; ++j)
            #pragma unroll
            for (int r = 0; r < 4; ++r)
                C[(size_t)(row0 + wm + 16 * i + quad * 4 + r) * N
                  + col0 + wn + 16 * j + ln] = acc[i][j][r];
}

// ---------------------------------------------------------------------------
extern "C" void kernel_launch(void* const* d_in, const int* in_sizes, int n_in,
                              void* d_out, int out_size, void* d_ws, size_t ws_size,
                              hipStream_t stream)
{
    const float* q  = (const float*)d_in[0];
    const float* Wq = (const float*)d_in[1];
    const float* Wk = (const float*)d_in[2];
    const float* Wv = (const float*)d_in[3];
    const float* Wo = (const float*)d_in[4];
    float* out = (float*)d_out;

    const int M = BATCH * SEQ;          // 4096

    // ws layout (r19): Abf bf16 [4096][1024] lives in the old XQKV slot
    // (XQKV eliminated by the fused epilogue).  WT bf16 [2048][1024] (AO32
    // aliases WT) | WoPt bf16 [1024][512] | Qp | Kb | Vtg -- offsets kept
    // from the r8-proven layout.
    short* Abf  = (short*)d_ws;
    short* WT   = (short*)((float*)d_ws + (size_t)M * 2048);
    short* WoPt = WT + (size_t)2048 * 1024;
    short* Qp   = WoPt + (size_t)1024 * 512;
    short* Kb   = Qp + (size_t)M * 512;
    short* Vtg  = Kb + (size_t)M * 512;
    short* AO32 = WT;   // alias

    dim3 blk(256);

    // 1) Weight prep + activation cvt, one launch
    prep_weights<<<dim3(32, 32, 6), blk, 0, stream>>>(Wq, Wk, Wv, Wo, WT, WoPt, q, Abf);

    // 2) QKV projection with fused rope/transpose epilogue -> Qp, Kb, Vtg
    gemm_qkv<<<dim3(16, 32), blk, 0, stream>>>(Abf, WT, Qp, Kb, Vtg);

    // 3) Flash attention (512 blocks x 512 threads) -> AO32 (aliases WT)
    flash_attn<<<BATCH * HEADS * (SEQ / 128), dim3(512), 0, stream>>>(Qp, Kb, Vtg, AO32);

    // 4) Output GEMM -> f32 out
    gemm_wo<<<dim3(8, 64), blk, 0, stream>>>(AO32, WoPt, out);
}

// Round 11
// 149.669 us; speedup vs baseline: 1.1475x; 1.1475x over previous
//
#include <hip/hip_runtime.h>
#include <hip/hip_bf16.h>
#include <math.h>

#define HEADS 16
#define KV_HEADS 8
#define DIMS 64
#define IN_DIMS 1024
#define BATCH 2
#define SEQ 2048

typedef __attribute__((ext_vector_type(8))) short short8;   // 8 bf16 (4 VGPRs)
typedef __attribute__((ext_vector_type(4))) float f32x4;    // MFMA accumulator
typedef __attribute__((ext_vector_type(4))) unsigned int u32x4;

__device__ __forceinline__ short f2bf(float f) {
    __hip_bfloat16 h = __float2bfloat16(f);
    return *reinterpret_cast<short*>(&h);
}

// Raw v_exp_f32 (exp2) -- r18-verified (libm exp2f carries range handling).
__device__ __forceinline__ float e2(float x) {
    return __builtin_amdgcn_exp2f(x);
}

// gfx950 packed f32->bf16.  m240: keep OUT of hot compute loops (r16: -4%);
// fine in memory-bound prep/epilogue code.
__device__ __forceinline__ unsigned int cvtpk(float a, float b) {
    unsigned int r;
    asm("v_cvt_pk_bf16_f32 %0, %1, %2" : "=v"(r) : "v"(a), "v"(b));
    return r;
}

// Direct global->LDS async copy, 16B per lane (m97 pattern).
__device__ __forceinline__ void gl_lds16(const void* g, void* l) {
    __builtin_amdgcn_global_load_lds(
        (const __attribute__((address_space(1))) unsigned int*)g,
        (__attribute__((address_space(3))) unsigned int*)l, 16, 0, 0);
}

#define LOG2_10000 13.287712379549449f
#define LOG2_2PI   2.6514961294723187f
#define CSCALE (0.5f * 1.4426950408889634f)   // attn scale * log2(e)

// Revolution-space sin/cos (r18-verified): v_sin/v_cos compute sin(x*2pi);
// fract() is the exact periodic reduction.  Angle err ~1e-4 rad << bf16 lsb.
__device__ __forceinline__ void sincos_rev(float ang_rev, float* sn, float* cs) {
    float fr = ang_rev - floorf(ang_rev);
    *sn = __builtin_amdgcn_sinf(fr);
    *cs = __builtin_amdgcn_cosf(fr);
}

// ---------------------------------------------------------------------------
// All weight prep + activation cvt in ONE launch (z-indexed).
//  z=0: WT[0:1024] = Wq^T   z=1: WT[1024:1536] = Wk^T   z=2: WT[1536:2048] = Wv^T
//  z=3: WoPt[n][d] = bf16(Wo[2d][n] + Wo[2d+1][n])
//  z=4,5: Abf = bf16(q)
// r20: z=0/z=1 rows are stored SIGMA-PERMUTED (within each 64-col group,
// GEMM col 16j+ln <-> orig col 2*ln+(j&1)+32*(j>=2)) so the rope pair
// (2u,2u+1) lands in the SAME lane of the QKV GEMM (acc[i][2jp]/[2jp+1]) --
// the fused epilogue then needs no cross-lane shuffles (r19's 55us killer).
// ---------------------------------------------------------------------------
__global__ __launch_bounds__(256) void prep_weights(
    const float* __restrict__ Wq, const float* __restrict__ Wk,
    const float* __restrict__ Wv, const float* __restrict__ Wo,
    short* __restrict__ WT, short* __restrict__ WoPt,
    const float* __restrict__ qin, short* __restrict__ Abf)
{
    __shared__ float t[32][33];
    int z = blockIdx.z;
    if (z >= 4) {
        int i = (z - 4) * 1024 + blockIdx.y * 32 + blockIdx.x;
        size_t idx = ((size_t)i * 256 + threadIdx.x) * 8;
        float4 a = *(const float4*)(qin + idx);
        float4 c = *(const float4*)(qin + idx + 4);
        u32x4 s = { cvtpk(a.x, a.y), cvtpk(a.z, a.w),
                    cvtpk(c.x, c.y), cvtpk(c.z, c.w) };
        *(u32x4*)(Abf + idx) = s;
        return;
    }
    int bx = blockIdx.x * 32, by = blockIdx.y * 32;
    int x = threadIdx.x & 31, y = threadIdx.x >> 5;
    if (z == 3) {
        if (by >= 512) return;
        #pragma unroll
        for (int i = 0; i < 32; i += 8) {
            int d = by + y + i;
            t[y + i][x] = Wo[(size_t)(2 * d) * 1024 + bx + x]
                        + Wo[(size_t)(2 * d + 1) * 1024 + bx + x];
        }
        __syncthreads();
        #pragma unroll
        for (int i = 0; i < 32; i += 8)
            WoPt[(size_t)(bx + y + i) * 512 + by + x] = f2bf(t[x][y + i]);
    } else {
        const float* W = (z == 0) ? Wq : ((z == 1) ? Wk : Wv);
        int N = (z == 0) ? 1024 : 512;
        if (bx >= N) return;
        short* dst = WT + ((z == 0) ? 0 : ((z == 1) ? (size_t)1024 * 1024
                                                    : (size_t)1536 * 1024));
        #pragma unroll
        for (int i = 0; i < 32; i += 8)
            t[y + i][x] = W[(size_t)(by + y + i) * N + bx + x];
        __syncthreads();
        #pragma unroll
        for (int i = 0; i < 32; i += 8) {
            int c = bx + y + i;          // orig col within region
            int g = c;
            if (z <= 1) {                // sigma-permute Q and K regions
                int oc = c & 63;
                g = (c & ~63) | (((oc & 1) | ((oc >> 5) << 1)) << 4)
                              | ((oc & 31) >> 1);
            }
            dst[(size_t)g * 1024 + by + x] = f2bf(t[x][y + i]);
        }
    }
}

// ---------------------------------------------------------------------------
// gemm_qkv (r20): QKV projection with fused rope/transpose epilogue, v2.
// Main loop identical to r18's gemm_af32 (BM=BN=128, BK=64, 4 waves,
// global_load_lds staging); B columns are sigma-permuted (see prep_weights)
// -- the main loop is oblivious.  Epilogue v2: rope pairs are IN-LANE
// (xe=acc[i][2jp][r], xo=acc[i][2jp+1][r]): zero shuffles, all 64 lanes
// store, trig halved vs r19 (32 sincos/lane), coalesced 32B/64B stores per
// quad-row.  Same per-output arithmetic as r18's prep_qkv -> bit-identical.
// ---------------------------------------------------------------------------
__global__ __launch_bounds__(256) void gemm_qkv(
    const short* __restrict__ A, const short* __restrict__ Bt,
    short* __restrict__ Qp, short* __restrict__ Kb, short* __restrict__ Vtg)
{
    const int K = 1024;
    __shared__ short As[128][64];
    __shared__ short Bs[128][64];

    int tid  = threadIdx.x;
    int lane = tid & 63, wave = tid >> 6;
    int quad = lane >> 4, ln = lane & 15;
    int wm = (wave >> 1) * 64, wn = (wave & 1) * 64;
    int row0 = blockIdx.y * 128, col0 = blockIdx.x * 128;

    int sr = lane >> 3;              // staging row within 8-row group
    int sk = (lane & 7) * 8;         // staging col (shorts)

    f32x4 acc[4][4] = {};

    for (int kt = 0; kt < K; kt += 64) {
        #pragma unroll
        for (int u = 0; u < 4; ++u) {
            int r = wave * 32 + u * 8;
            gl_lds16(A + (size_t)(row0 + r + sr) * K + kt + sk, &As[r][0]);
        }
        #pragma unroll
        for (int u = 0; u < 4; ++u) {
            int r = wave * 32 + u * 8;
            gl_lds16(Bt + (size_t)(col0 + r + sr) * K + kt + sk, &Bs[r][0]);
        }
        __syncthreads();

        #pragma unroll
        for (int k0 = 0; k0 < 64; k0 += 32) {
            short8 af[4], bfr[4];
            #pragma unroll
            for (int i = 0; i < 4; ++i)
                af[i] = *(const short8*)&As[wm + 16 * i + ln][k0 + quad * 8];
            #pragma unroll
            for (int j = 0; j < 4; ++j)
                bfr[j] = *(const short8*)&Bs[wn + 16 * j + ln][k0 + quad * 8];
            #pragma unroll
            for (int i = 0; i < 4; ++i)
                #pragma unroll
                for (int j = 0; j < 4; ++j)
                    acc[i][j] = __builtin_amdgcn_mfma_f32_16x16x32_bf16(
                        af[i], bfr[j], acc[i][j], 0, 0, 0);
        }
        __syncthreads();
    }

    // ----- fused epilogue v2 (in-lane pairs, no shuffles) -----
    if (col0 < 1024) {
        // Q: rope + pairsum + scale -> Qp[row][u], u = output col
        int ubase = (col0 + wn) >> 1;
        #pragma unroll
        for (int jp = 0; jp < 2; ++jp) {
            int u = ubase + jp * 16 + ln;
            float tr = e2(-(float)u / 512.f * LOG2_10000 - LOG2_2PI);
            #pragma unroll
            for (int i = 0; i < 4; ++i) {
                int rowb = row0 + wm + 16 * i + quad * 4;
                #pragma unroll
                for (int r = 0; r < 4; ++r) {
                    int row = rowb + r;
                    float sn, cs;
                    sincos_rev((float)((row & (SEQ - 1)) + 1) * tr, &sn, &cs);
                    float xe = acc[i][2 * jp][r], xo = acc[i][2 * jp + 1][r];
                    Qp[(size_t)row * 512 + u] =
                        f2bf((xe * (cs + sn) + xo * (cs - sn)) * CSCALE);
                }
            }
        }
    } else if (col0 < 1536) {
        // K: rope -> Kb[row][{2p,2p+1}] as one u32 per lane
        int pbase = (col0 - 1024 + wn) >> 1;
        #pragma unroll
        for (int jp = 0; jp < 2; ++jp) {
            int p = pbase + jp * 16 + ln;
            float tr = e2(-(float)p / 256.f * LOG2_10000 - LOG2_2PI);
            #pragma unroll
            for (int i = 0; i < 4; ++i) {
                int rowb = row0 + wm + 16 * i + quad * 4;
                #pragma unroll
                for (int r = 0; r < 4; ++r) {
                    int row = rowb + r;
                    float sn, cs;
                    sincos_rev((float)((row & (SEQ - 1)) + 1) * tr, &sn, &cs);
                    float xe = acc[i][2 * jp][r], xo = acc[i][2 * jp + 1][r];
                    *(unsigned int*)(Kb + (size_t)row * 512 + 2 * p) =
                        cvtpk(xe * cs - xo * sn, xe * sn + xo * cs);
                }
            }
        }
    } else {
        // V: transposed bf16 store -> Vtg[b][dim][key] (short4 = 4 keys)
        int b = row0 >> 11;
        int s0 = (row0 & (SEQ - 1)) + wm + quad * 4;
        #pragma unroll
        for (int j = 0; j < 4; ++j) {
            int dim = col0 + wn + 16 * j + ln - 1536;
            short* dst = Vtg + ((size_t)(b * 512 + dim)) * SEQ + s0;
            #pragma unroll
            for (int i = 0; i < 4; ++i) {
                short4 o4 = { f2bf(acc[i][j][0]), f2bf(acc[i][j][1]),
                              f2bf(acc[i][j][2]), f2bf(acc[i][j][3]) };
                *(short4*)(dst + 16 * i) = o4;
            }
        }
    }
}

// ---------------------------------------------------------------------------
// MFMA flash attention (r18-verified, UNCHANGED).  8-wave QBLK=128;
// K/V staging split by wave-group; 1 global load + 1 ds_write per thread
// per tile; 1 barrier/tile; raw v_exp_f32 softmax.
//
// ZERO-LDS softmax path (both MFMAs operand-swapped):
//   QK^T:  sc = mfma(Kfrag, Qfrag)  -> lane (quad,ln) holds S[key][q=qw+ln]
//   PV^T:  O^T = mfma(Vfrag, Pfrag) <- P packed in-register as B-fragments
// K rows stored pi-PERMUTED in LDS (key[k5 k4 k3 k2 k1 k0] ->
// row[k5 k2 k4 k3 k1 k0]) so sc lands exactly in PV-B arrangement:
//   sc[j0][r] = S[key = 32*(j0>>1) + 8*quad + 4*(j0&1) + r][q]
// LDS: Qs[128][40] + Ks[2][64][40] + Vt[2][32][72] = 29.7 KB.
// ---------------------------------------------------------------------------
__global__ __launch_bounds__(512) void flash_attn(
    const short* __restrict__ Qp, const short* __restrict__ Kb,
    const short* __restrict__ Vtg, short* __restrict__ AO32)
{
    __shared__ short Qs[128][40];
    __shared__ short Ks[2][64][40];
    __shared__ short Vt[2][32][72];

    int tid = threadIdx.x;                // 0..511
    int qt = blockIdx.x & 15;             // SEQ/128 q-tiles
    int h  = (blockIdx.x >> 4) & 15;
    int b  = blockIdx.x >> 8;

    int lane = tid & 63, wave = tid >> 6; // 8 waves
    int quad = lane >> 4, ln = lane & 15;
    int qw = wave * 16;

    // Stage Q tile: 128 rows x 32 bf16 (1 short8/thread, 512 threads)
    {
        int row = tid >> 2, off = (tid & 3) * 8;
        *(short8*)&Qs[row][off] =
            *(const short8*)(Qp + (size_t)(b * SEQ + qt * 128 + row) * 512 + h * 32 + off);
    }

    const short* Kgb = Kb + (size_t)(b * SEQ) * 512 + 32 * h;
    const short* Vgb = Vtg + ((size_t)b * 512 + 32 * h) * SEQ;

    // Staging roles: waves 0-3 stage K (pi-permuted rows), waves 4-7 stage V.
    bool doK = tid < 256;
    int st = tid & 255;
    int krow = st >> 2, koff = (st & 3) * 8;      // K: 64 keys x 32 bf16
    int prow = ((krow >> 5) << 5) | (((krow >> 2) & 1) << 4)
             | (((krow >> 3) & 3) << 2) | (krow & 3);
    int vrow = st >> 3, voff = (st & 7) * 8;      // V: 32 dims x 64 keys

    // Prologue: stage tile 0 into buffer 0 (wave-uniform branch)
    short8 sreg;
    if (doK) {
        sreg = *(const short8*)(Kgb + (size_t)krow * 512 + koff);
        *(short8*)&Ks[0][prow][koff] = sreg;
    } else {
        sreg = *(const short8*)(Vgb + (size_t)vrow * SEQ + voff);
        *(short8*)&Vt[0][vrow][voff] = sreg;
    }
    __syncthreads();

    short8 af = *(const short8*)&Qs[qw + ln][quad * 8];   // loop-invariant

    float lsum = 0.f;                   // softmax denom partial, query qw+ln
    f32x4 Oacc[2] = {};
    const f32x4 zz = {};                // hoisted zero accumulator regs

    for (int t = 0; t < 32; ++t) {
        int cur = t & 1;

        // Issue next-tile global load early (hides under compute)
        if (t < 31) {
            int ktn = (t + 1) * 64;
            if (doK)
                sreg = *(const short8*)(Kgb + (size_t)(ktn + krow) * 512 + koff);
            else
                sreg = *(const short8*)(Vgb + (size_t)vrow * SEQ + ktn + voff);
        }

        // Swapped QK^T on pi-permuted K rows:
        // sc[j0][r] = S[key = 32*(j0>>1) + 8*quad + 4*(j0&1) + r][q=qw+ln]
        f32x4 sc[4];
        __builtin_amdgcn_s_setprio(1);
        #pragma unroll
        for (int j0 = 0; j0 < 4; ++j0) {
            short8 kf = *(const short8*)&Ks[cur][j0 * 16 + ln][quad * 8];
            sc[j0] = __builtin_amdgcn_mfma_f32_16x16x32_bf16(kf, af, zz, 0, 0, 0);
        }
        __builtin_amdgcn_s_setprio(0);

        // No-max softmax numerators via raw v_exp_f32, packed IN-REGISTER
        // as PV B-fragments (f2bf per m240).
        short8 pf[2];
        #pragma unroll
        for (int kg = 0; kg < 2; ++kg) {
            float p0 = e2(sc[2 * kg][0]);
            float p1 = e2(sc[2 * kg][1]);
            float p2 = e2(sc[2 * kg][2]);
            float p3 = e2(sc[2 * kg][3]);
            float p4 = e2(sc[2 * kg + 1][0]);
            float p5 = e2(sc[2 * kg + 1][1]);
            float p6 = e2(sc[2 * kg + 1][2]);
            float p7 = e2(sc[2 * kg + 1][3]);
            lsum += ((p0 + p1) + (p2 + p3)) + ((p4 + p5) + (p6 + p7));
            short8 s = { f2bf(p0), f2bf(p1), f2bf(p2), f2bf(p3),
                         f2bf(p4), f2bf(p5), f2bf(p6), f2bf(p7) };
            pf[kg] = s;
        }

        // Swapped PV: Oacc[ng] = O^T tile, A = V^T fragment, B = pf (regs).
        __builtin_amdgcn_s_setprio(1);
        #pragma unroll
        for (int kg = 0; kg < 2; ++kg) {
            #pragma unroll
            for (int ng = 0; ng < 2; ++ng) {
                short8 vf = *(const short8*)&Vt[cur][ng * 16 + ln][kg * 32 + quad * 8];
                Oacc[ng] = __builtin_amdgcn_mfma_f32_16x16x32_bf16(
                    vf, pf[kg], Oacc[ng], 0, 0, 0);
            }
        }
        __builtin_amdgcn_s_setprio(0);

        // Write next tile into the other buffer (read side drained by the
        // barrier at the end of the PREVIOUS iteration).
        if (t < 31) {
            if (doK) *(short8*)&Ks[cur ^ 1][prow][koff] = sreg;
            else     *(short8*)&Vt[cur ^ 1][vrow][voff] = sreg;
        }
        __syncthreads();
    }

    // Denominator: quads hold disjoint key subsets of the SAME query qw+ln
    lsum += __shfl_xor(lsum, 16);
    lsum += __shfl_xor(lsum, 32);
    float inv = 1.f / lsum;

    // Epilogue: lane (quad,ln) holds O^T[d = ng*16 + quad*4 + r][q = qw+ln]
    size_t row = (size_t)(b * SEQ) + qt * 128 + qw + ln;
    #pragma unroll
    for (int ng = 0; ng < 2; ++ng) {
        short4 o4 = { f2bf(Oacc[ng][0] * inv), f2bf(Oacc[ng][1] * inv),
                      f2bf(Oacc[ng][2] * inv), f2bf(Oacc[ng][3] * inv) };
        *(short4*)&AO32[row * 512 + h * 32 + ng * 16 + quad * 4] = o4;
    }
}

// ---------------------------------------------------------------------------
// Output GEMM: out[4096][1024] = AO32[4096][512] @ WoPt[1024][512]^T.
// BM=64, BN=128; global_load_lds staging, linear LDS (r13).
// ---------------------------------------------------------------------------
__global__ __launch_bounds__(256) void gemm_wo(
    const short* __restrict__ A, const short* __restrict__ Bt,
    float* __restrict__ C)
{
    __shared__ short As[64][64];
    __shared__ short Bs[128][64];

    int tid  = threadIdx.x;
    int lane = tid & 63, wave = tid >> 6;
    int quad = lane >> 4, ln = lane & 15;
    int wm = (wave >> 1) * 32, wn = (wave & 1) * 64;
    int row0 = blockIdx.y * 64, col0 = blockIdx.x * 128;
    const int K = 512, N = 1024;

    int sr = lane >> 3;
    int sk = (lane & 7) * 8;

    f32x4 acc[2][4] = {};

    for (int kt = 0; kt < K; kt += 64) {
        #pragma unroll
        for (int u = 0; u < 2; ++u) {
            int r = wave * 16 + u * 8;
            gl_lds16(A + (size_t)(row0 + r + sr) * K + kt + sk, &As[r][0]);
        }
        #pragma unroll
        for (int u = 0; u < 4; ++u) {
            int r = wave * 32 + u * 8;
            gl_lds16(Bt + (size_t)(col0 + r + sr) * K + kt + sk, &Bs[r][0]);
        }
        __syncthreads();

        #pragma unroll
        for (int k0 = 0; k0 < 64; k0 += 32) {
            short8 af[2], bfr[4];
            #pragma unroll
            for (int i = 0; i < 2; ++i)
                af[i] = *(const short8*)&As[wm + 16 * i + ln][k0 + quad * 8];
            #pragma unroll
            for (int j = 0; j < 4; ++j)
                bfr[j] = *(const short8*)&Bs[wn + 16 * j + ln][k0 + quad * 8];
            #pragma unroll
            for (int i = 0; i < 2; ++i)
                #pragma unroll
                for (int j = 0; j < 4; ++j)
                    acc[i][j] = __builtin_amdgcn_mfma_f32_16x16x32_bf16(
                        af[i], bfr[j], acc[i][j], 0, 0, 0);
        }
        __syncthreads();
    }

    #pragma unroll
    for (int i = 0; i < 2; ++i)
        #pragma unroll
        for (int j = 0; j < 4; ++j)
            #pragma unroll
            for (int r = 0; r < 4; ++r)
                C[(size_t)(row0 + wm + 16 * i + quad * 4 + r) * N
                  + col0 + wn + 16 * j + ln] = acc[i][j][r];
}

// ---------------------------------------------------------------------------
extern "C" void kernel_launch(void* const* d_in, const int* in_sizes, int n_in,
                              void* d_out, int out_size, void* d_ws, size_t ws_size,
                              hipStream_t stream)
{
    const float* q  = (const float*)d_in[0];
    const float* Wq = (const float*)d_in[1];
    const float* Wk = (const float*)d_in[2];
    const float* Wv = (const float*)d_in[3];
    const float* Wo = (const float*)d_in[4];
    float* out = (float*)d_out;

    const int M = BATCH * SEQ;          // 4096

    // ws layout (r19/r20): Abf bf16 [4096][1024] in the old XQKV slot.
    // WT bf16 [2048][1024] (AO32 aliases WT) | WoPt | Qp | Kb | Vtg.
    short* Abf  = (short*)d_ws;
    short* WT   = (short*)((float*)d_ws + (size_t)M * 2048);
    short* WoPt = WT + (size_t)2048 * 1024;
    short* Qp   = WoPt + (size_t)1024 * 512;
    short* Kb   = Qp + (size_t)M * 512;
    short* Vtg  = Kb + (size_t)M * 512;
    short* AO32 = WT;   // alias

    dim3 blk(256);

    // 1) Weight prep (sigma-permuted Q/K regions) + activation cvt
    prep_weights<<<dim3(32, 32, 6), blk, 0, stream>>>(Wq, Wk, Wv, Wo, WT, WoPt, q, Abf);

    // 2) QKV projection with fused in-lane rope/transpose epilogue
    gemm_qkv<<<dim3(16, 32), blk, 0, stream>>>(Abf, WT, Qp, Kb, Vtg);

    // 3) Flash attention (512 blocks x 512 threads) -> AO32 (aliases WT)
    flash_attn<<<BATCH * HEADS * (SEQ / 128), dim3(512), 0, stream>>>(Qp, Kb, Vtg, AO32);

    // 4) Output GEMM -> f32 out
    gemm_wo<<<dim3(8, 64), blk, 0, stream>>>(AO32, WoPt, out);
}

// Round 12
// 148.285 us; speedup vs baseline: 1.1582x; 1.0093x over previous
//
#include <hip/hip_runtime.h>
#include <hip/hip_bf16.h>
#include <math.h>

#define HEADS 16
#define KV_HEADS 8
#define DIMS 64
#define IN_DIMS 1024
#define BATCH 2
#define SEQ 2048

typedef __attribute__((ext_vector_type(8))) short short8;   // 8 bf16 (4 VGPRs)
typedef __attribute__((ext_vector_type(4))) float f32x4;    // MFMA accumulator
typedef __attribute__((ext_vector_type(4))) unsigned int u32x4;

__device__ __forceinline__ short f2bf(float f) {
    __hip_bfloat16 h = __float2bfloat16(f);
    return *reinterpret_cast<short*>(&h);
}

// Raw v_exp_f32 (exp2) -- r18-verified (libm exp2f carries range handling).
__device__ __forceinline__ float e2(float x) {
    return __builtin_amdgcn_exp2f(x);
}

// gfx950 packed f32->bf16.  m240: keep OUT of hot compute loops (r16: -4%);
// fine in memory-bound prep/epilogue code.
__device__ __forceinline__ unsigned int cvtpk(float a, float b) {
    unsigned int r;
    asm("v_cvt_pk_bf16_f32 %0, %1, %2" : "=v"(r) : "v"(a), "v"(b));
    return r;
}

// Direct global->LDS async copy, 16B per lane (m97 pattern).
__device__ __forceinline__ void gl_lds16(const void* g, void* l) {
    __builtin_amdgcn_global_load_lds(
        (const __attribute__((address_space(1))) unsigned int*)g,
        (__attribute__((address_space(3))) unsigned int*)l, 16, 0, 0);
}

#define LOG2_10000 13.287712379549449f
#define LOG2_2PI   2.6514961294723187f
#define CSCALE (0.5f * 1.4426950408889634f)   // attn scale * log2(e)

// Revolution-space sin/cos (r18-verified): v_sin/v_cos compute sin(x*2pi);
// fract() is the exact periodic reduction.  Angle err ~1e-4 rad << bf16 lsb.
__device__ __forceinline__ void sincos_rev(float ang_rev, float* sn, float* cs) {
    float fr = ang_rev - floorf(ang_rev);
    *sn = __builtin_amdgcn_sinf(fr);
    *cs = __builtin_amdgcn_cosf(fr);
}

// ---------------------------------------------------------------------------
// All weight prep + activation cvt in ONE launch (z-indexed).
//  z=0: WT[0:1024] = Wq^T   z=1: WT[1024:1536] = Wk^T   z=2: WT[1536:2048] = Wv^T
//  z=3: WoPt[n][d] = bf16(Wo[2d][n] + Wo[2d+1][n])
//  z=4,5: Abf = bf16(q)
// r20: z=0/z=1 rows stored SIGMA-PERMUTED (within each 64-col group,
// GEMM col 16j+ln <-> orig col 2*ln+(j&1)+32*(j>=2)) so rope pairs land
// in-lane in the QKV GEMM epilogue (r20-verified).
// ---------------------------------------------------------------------------
__global__ __launch_bounds__(256) void prep_weights(
    const float* __restrict__ Wq, const float* __restrict__ Wk,
    const float* __restrict__ Wv, const float* __restrict__ Wo,
    short* __restrict__ WT, short* __restrict__ WoPt,
    const float* __restrict__ qin, short* __restrict__ Abf)
{
    __shared__ float t[32][33];
    int z = blockIdx.z;
    if (z >= 4) {
        int i = (z - 4) * 1024 + blockIdx.y * 32 + blockIdx.x;
        size_t idx = ((size_t)i * 256 + threadIdx.x) * 8;
        float4 a = *(const float4*)(qin + idx);
        float4 c = *(const float4*)(qin + idx + 4);
        u32x4 s = { cvtpk(a.x, a.y), cvtpk(a.z, a.w),
                    cvtpk(c.x, c.y), cvtpk(c.z, c.w) };
        *(u32x4*)(Abf + idx) = s;
        return;
    }
    int bx = blockIdx.x * 32, by = blockIdx.y * 32;
    int x = threadIdx.x & 31, y = threadIdx.x >> 5;
    if (z == 3) {
        if (by >= 512) return;
        #pragma unroll
        for (int i = 0; i < 32; i += 8) {
            int d = by + y + i;
            t[y + i][x] = Wo[(size_t)(2 * d) * 1024 + bx + x]
                        + Wo[(size_t)(2 * d + 1) * 1024 + bx + x];
        }
        __syncthreads();
        #pragma unroll
        for (int i = 0; i < 32; i += 8)
            WoPt[(size_t)(bx + y + i) * 512 + by + x] = f2bf(t[x][y + i]);
    } else {
        const float* W = (z == 0) ? Wq : ((z == 1) ? Wk : Wv);
        int N = (z == 0) ? 1024 : 512;
        if (bx >= N) return;
        short* dst = WT + ((z == 0) ? 0 : ((z == 1) ? (size_t)1024 * 1024
                                                    : (size_t)1536 * 1024));
        #pragma unroll
        for (int i = 0; i < 32; i += 8)
            t[y + i][x] = W[(size_t)(by + y + i) * N + bx + x];
        __syncthreads();
        #pragma unroll
        for (int i = 0; i < 32; i += 8) {
            int c = bx + y + i;          // orig col within region
            int g = c;
            if (z <= 1) {                // sigma-permute Q and K regions
                int oc = c & 63;
                g = (c & ~63) | (((oc & 1) | ((oc >> 5) << 1)) << 4)
                              | ((oc & 31) >> 1);
            }
            dst[(size_t)g * 1024 + by + x] = f2bf(t[x][y + i]);
        }
    }
}

// ---------------------------------------------------------------------------
// gemm_qkv (r20-verified): QKV projection with fused in-lane rope/transpose
// epilogue.  Main loop = m97-pattern 128x128 (global_load_lds staging).
// ---------------------------------------------------------------------------
__global__ __launch_bounds__(256) void gemm_qkv(
    const short* __restrict__ A, const short* __restrict__ Bt,
    short* __restrict__ Qp, short* __restrict__ Kb, short* __restrict__ Vtg)
{
    const int K = 1024;
    __shared__ short As[128][64];
    __shared__ short Bs[128][64];

    int tid  = threadIdx.x;
    int lane = tid & 63, wave = tid >> 6;
    int quad = lane >> 4, ln = lane & 15;
    int wm = (wave >> 1) * 64, wn = (wave & 1) * 64;
    int row0 = blockIdx.y * 128, col0 = blockIdx.x * 128;

    int sr = lane >> 3;              // staging row within 8-row group
    int sk = (lane & 7) * 8;         // staging col (shorts)

    f32x4 acc[4][4] = {};

    for (int kt = 0; kt < K; kt += 64) {
        #pragma unroll
        for (int u = 0; u < 4; ++u) {
            int r = wave * 32 + u * 8;
            gl_lds16(A + (size_t)(row0 + r + sr) * K + kt + sk, &As[r][0]);
        }
        #pragma unroll
        for (int u = 0; u < 4; ++u) {
            int r = wave * 32 + u * 8;
            gl_lds16(Bt + (size_t)(col0 + r + sr) * K + kt + sk, &Bs[r][0]);
        }
        __syncthreads();

        #pragma unroll
        for (int k0 = 0; k0 < 64; k0 += 32) {
            short8 af[4], bfr[4];
            #pragma unroll
            for (int i = 0; i < 4; ++i)
                af[i] = *(const short8*)&As[wm + 16 * i + ln][k0 + quad * 8];
            #pragma unroll
            for (int j = 0; j < 4; ++j)
                bfr[j] = *(const short8*)&Bs[wn + 16 * j + ln][k0 + quad * 8];
            #pragma unroll
            for (int i = 0; i < 4; ++i)
                #pragma unroll
                for (int j = 0; j < 4; ++j)
                    acc[i][j] = __builtin_amdgcn_mfma_f32_16x16x32_bf16(
                        af[i], bfr[j], acc[i][j], 0, 0, 0);
        }
        __syncthreads();
    }

    // ----- fused epilogue v2 (in-lane pairs, no shuffles; r20-verified) -----
    if (col0 < 1024) {
        int ubase = (col0 + wn) >> 1;
        #pragma unroll
        for (int jp = 0; jp < 2; ++jp) {
            int u = ubase + jp * 16 + ln;
            float tr = e2(-(float)u / 512.f * LOG2_10000 - LOG2_2PI);
            #pragma unroll
            for (int i = 0; i < 4; ++i) {
                int rowb = row0 + wm + 16 * i + quad * 4;
                #pragma unroll
                for (int r = 0; r < 4; ++r) {
                    int row = rowb + r;
                    float sn, cs;
                    sincos_rev((float)((row & (SEQ - 1)) + 1) * tr, &sn, &cs);
                    float xe = acc[i][2 * jp][r], xo = acc[i][2 * jp + 1][r];
                    Qp[(size_t)row * 512 + u] =
                        f2bf((xe * (cs + sn) + xo * (cs - sn)) * CSCALE);
                }
            }
        }
    } else if (col0 < 1536) {
        int pbase = (col0 - 1024 + wn) >> 1;
        #pragma unroll
        for (int jp = 0; jp < 2; ++jp) {
            int p = pbase + jp * 16 + ln;
            float tr = e2(-(float)p / 256.f * LOG2_10000 - LOG2_2PI);
            #pragma unroll
            for (int i = 0; i < 4; ++i) {
                int rowb = row0 + wm + 16 * i + quad * 4;
                #pragma unroll
                for (int r = 0; r < 4; ++r) {
                    int row = rowb + r;
                    float sn, cs;
                    sincos_rev((float)((row & (SEQ - 1)) + 1) * tr, &sn, &cs);
                    float xe = acc[i][2 * jp][r], xo = acc[i][2 * jp + 1][r];
                    *(unsigned int*)(Kb + (size_t)row * 512 + 2 * p) =
                        cvtpk(xe * cs - xo * sn, xe * sn + xo * cs);
                }
            }
        }
    } else {
        int b = row0 >> 11;
        int s0 = (row0 & (SEQ - 1)) + wm + quad * 4;
        #pragma unroll
        for (int j = 0; j < 4; ++j) {
            int dim = col0 + wn + 16 * j + ln - 1536;
            short* dst = Vtg + ((size_t)(b * 512 + dim)) * SEQ + s0;
            #pragma unroll
            for (int i = 0; i < 4; ++i) {
                short4 o4 = { f2bf(acc[i][j][0]), f2bf(acc[i][j][1]),
                              f2bf(acc[i][j][2]), f2bf(acc[i][j][3]) };
                *(short4*)(dst + 16 * i) = o4;
            }
        }
    }
}

// ---------------------------------------------------------------------------
// MFMA flash attention (r21 = r18 structure + DEPTH-2 staging pipeline).
// The r18/r20 loop issued load(t+1) and ds_wrote it in the SAME iteration:
// the ds_write's implicit wait is vmcnt(0) on a load with only ~1 compute
// phase of slack vs L3/HBM latency -> per-tile stall + barrier convoy.
// r21 loads TWO tiles ahead: iteration t issues load(t+2), computes t, and
// ds_writes the t+1 data loaded LAST iteration -- the write's register dep
// has a full tile of slack and the newer load stays outstanding (compiler
// emits the counted vmcnt, T4-style, no inline asm).  Same addresses, same
// data, same barrier/hazard structure -> bit-identical numerics.  +8 VGPR
// (register-rotated via unroll-2, static indexing per rule #20).
//
// 8-wave QBLK=128; K/V staging split by wave-group; raw v_exp_f32 softmax;
// ZERO-LDS softmax path (operand-swapped QK^T and PV^T, pi-permuted K).
// LDS: Qs[128][40] + Ks[2][64][40] + Vt[2][32][72] = 29.7 KB.
// ---------------------------------------------------------------------------
__global__ __launch_bounds__(512) void flash_attn(
    const short* __restrict__ Qp, const short* __restrict__ Kb,
    const short* __restrict__ Vtg, short* __restrict__ AO32)
{
    __shared__ short Qs[128][40];
    __shared__ short Ks[2][64][40];
    __shared__ short Vt[2][32][72];

    int tid = threadIdx.x;                // 0..511
    int qt = blockIdx.x & 15;             // SEQ/128 q-tiles
    int h  = (blockIdx.x >> 4) & 15;
    int b  = blockIdx.x >> 8;

    int lane = tid & 63, wave = tid >> 6; // 8 waves
    int quad = lane >> 4, ln = lane & 15;
    int qw = wave * 16;

    // Stage Q tile: 128 rows x 32 bf16 (1 short8/thread, 512 threads)
    {
        int row = tid >> 2, off = (tid & 3) * 8;
        *(short8*)&Qs[row][off] =
            *(const short8*)(Qp + (size_t)(b * SEQ + qt * 128 + row) * 512 + h * 32 + off);
    }

    const short* Kgb = Kb + (size_t)(b * SEQ) * 512 + 32 * h;
    const short* Vgb = Vtg + ((size_t)b * 512 + 32 * h) * SEQ;

    // Staging roles: waves 0-3 stage K (pi-permuted rows), waves 4-7 stage V.
    bool doK = tid < 256;
    int st = tid & 255;
    int krow = st >> 2, koff = (st & 3) * 8;      // K: 64 keys x 32 bf16
    int prow = ((krow >> 5) << 5) | (((krow >> 2) & 1) << 4)
             | (((krow >> 3) & 3) << 2) | (krow & 3);
    int vrow = st >> 3, voff = (st & 7) * 8;      // V: 32 dims x 64 keys

    // Per-thread global source address (advances by 64 keys per tile)
    const short* gsrc = doK ? (Kgb + (size_t)krow * 512 + koff)
                            : (Vgb + (size_t)vrow * SEQ + voff);
    size_t gstep = doK ? (size_t)64 * 512 : (size_t)64;   // 64-key stride
    // LDS dest within a buffer
    short* ldst0 = doK ? &Ks[0][prow][koff] : &Vt[0][vrow][voff];
    short* ldst1 = doK ? &Ks[1][prow][koff] : &Vt[1][vrow][voff];

    // Prologue: stage tile 0; prefetch tile 1 into reg (depth-2 pipeline)
    short8 r0 = *(const short8*)(gsrc);
    *(short8*)ldst0 = r0;
    short8 nxt = *(const short8*)(gsrc + gstep);
    __syncthreads();

    short8 af = *(const short8*)&Qs[qw + ln][quad * 8];   // loop-invariant

    float lsum = 0.f;                   // softmax denom partial, query qw+ln
    f32x4 Oacc[2] = {};
    const f32x4 zz = {};                // hoisted zero accumulator regs

    #pragma unroll 2
    for (int t = 0; t < 32; ++t) {
        int cur = t & 1;

        // Issue load for tile t+2 (2-deep; consumed NEXT iteration)
        short8 nn;
        if (t < 30)
            nn = *(const short8*)(gsrc + (size_t)(t + 2) * gstep);

        // Swapped QK^T on pi-permuted K rows:
        // sc[j0][r] = S[key = 32*(j0>>1) + 8*quad + 4*(j0&1) + r][q=qw+ln]
        f32x4 sc[4];
        __builtin_amdgcn_s_setprio(1);
        #pragma unroll
        for (int j0 = 0; j0 < 4; ++j0) {
            short8 kf = *(const short8*)&Ks[cur][j0 * 16 + ln][quad * 8];
            sc[j0] = __builtin_amdgcn_mfma_f32_16x16x32_bf16(kf, af, zz, 0, 0, 0);
        }
        __builtin_amdgcn_s_setprio(0);

        // No-max softmax numerators via raw v_exp_f32, packed IN-REGISTER
        // as PV B-fragments (f2bf per m240).
        short8 pf[2];
        #pragma unroll
        for (int kg = 0; kg < 2; ++kg) {
            float p0 = e2(sc[2 * kg][0]);
            float p1 = e2(sc[2 * kg][1]);
            float p2 = e2(sc[2 * kg][2]);
            float p3 = e2(sc[2 * kg][3]);
            float p4 = e2(sc[2 * kg + 1][0]);
            float p5 = e2(sc[2 * kg + 1][1]);
            float p6 = e2(sc[2 * kg + 1][2]);
            float p7 = e2(sc[2 * kg + 1][3]);
            lsum += ((p0 + p1) + (p2 + p3)) + ((p4 + p5) + (p6 + p7));
            short8 s = { f2bf(p0), f2bf(p1), f2bf(p2), f2bf(p3),
                         f2bf(p4), f2bf(p5), f2bf(p6), f2bf(p7) };
            pf[kg] = s;
        }

        // Swapped PV: Oacc[ng] = O^T tile, A = V^T fragment, B = pf (regs).
        __builtin_amdgcn_s_setprio(1);
        #pragma unroll
        for (int kg = 0; kg < 2; ++kg) {
            #pragma unroll
            for (int ng = 0; ng < 2; ++ng) {
                short8 vf = *(const short8*)&Vt[cur][ng * 16 + ln][kg * 32 + quad * 8];
                Oacc[ng] = __builtin_amdgcn_mfma_f32_16x16x32_bf16(
                    vf, pf[kg], Oacc[ng], 0, 0, 0);
            }
        }
        __builtin_amdgcn_s_setprio(0);

        // ds_write tile t+1 data (loaded LAST iteration -> full tile of
        // latency slack; the t+2 load stays outstanding = counted vmcnt).
        if (t < 31)
            *(short8*)((cur ^ 1) ? ldst1 : ldst0) = nxt;
        nxt = nn;                       // rotate (copy-propagated by unroll)
        __syncthreads();
    }

    // Denominator: quads hold disjoint key subsets of the SAME query qw+ln
    lsum += __shfl_xor(lsum, 16);
    lsum += __shfl_xor(lsum, 32);
    float inv = 1.f / lsum;

    // Epilogue: lane (quad,ln) holds O^T[d = ng*16 + quad*4 + r][q = qw+ln]
    size_t row = (size_t)(b * SEQ) + qt * 128 + qw + ln;
    #pragma unroll
    for (int ng = 0; ng < 2; ++ng) {
        short4 o4 = { f2bf(Oacc[ng][0] * inv), f2bf(Oacc[ng][1] * inv),
                      f2bf(Oacc[ng][2] * inv), f2bf(Oacc[ng][3] * inv) };
        *(short4*)&AO32[row * 512 + h * 32 + ng * 16 + quad * 4] = o4;
    }
}

// ---------------------------------------------------------------------------
// Output GEMM: out[4096][1024] = AO32[4096][512] @ WoPt[1024][512]^T.
// BM=64, BN=128; global_load_lds staging, linear LDS (r13).
// ---------------------------------------------------------------------------
__global__ __launch_bounds__(256) void gemm_wo(
    const short* __restrict__ A, const short* __restrict__ Bt,
    float* __restrict__ C)
{
    __shared__ short As[64][64];
    __shared__ short Bs[128][64];

    int tid  = threadIdx.x;
    int lane = tid & 63, wave = tid >> 6;
    int quad = lane >> 4, ln = lane & 15;
    int wm = (wave >> 1) * 32, wn = (wave & 1) * 64;
    int row0 = blockIdx.y * 64, col0 = blockIdx.x * 128;
    const int K = 512, N = 1024;

    int sr = lane >> 3;
    int sk = (lane & 7) * 8;

    f32x4 acc[2][4] = {};

    for (int kt = 0; kt < K; kt += 64) {
        #pragma unroll
        for (int u = 0; u < 2; ++u) {
            int r = wave * 16 + u * 8;
            gl_lds16(A + (size_t)(row0 + r + sr) * K + kt + sk, &As[r][0]);
        }
        #pragma unroll
        for (int u = 0; u < 4; ++u) {
            int r = wave * 32 + u * 8;
            gl_lds16(Bt + (size_t)(col0 + r + sr) * K + kt + sk, &Bs[r][0]);
        }
        __syncthreads();

        #pragma unroll
        for (int k0 = 0; k0 < 64; k0 += 32) {
            short8 af[2], bfr[4];
            #pragma unroll
            for (int i = 0; i < 2; ++i)
                af[i] = *(const short8*)&As[wm + 16 * i + ln][k0 + quad * 8];
            #pragma unroll
            for (int j = 0; j < 4; ++j)
                bfr[j] = *(const short8*)&Bs[wn + 16 * j + ln][k0 + quad * 8];
            #pragma unroll
            for (int i = 0; i < 2; ++i)
                #pragma unroll
                for (int j = 0; j < 4; ++j)
                    acc[i][j] = __builtin_amdgcn_mfma_f32_16x16x32_bf16(
                        af[i], bfr[j], acc[i][j], 0, 0, 0);
        }
        __syncthreads();
    }

    #pragma unroll
    for (int i = 0; i < 2; ++i)
        #pragma unroll
        for (int j = 0; j < 4; ++j)
            #pragma unroll
            for (int r = 0; r < 4; ++r)
                C[(size_t)(row0 + wm + 16 * i + quad * 4 + r) * N
                  + col0 + wn + 16 * j + ln] = acc[i][j][r];
}

// ---------------------------------------------------------------------------
extern "C" void kernel_launch(void* const* d_in, const int* in_sizes, int n_in,
                              void* d_out, int out_size, void* d_ws, size_t ws_size,
                              hipStream_t stream)
{
    const float* q  = (const float*)d_in[0];
    const float* Wq = (const float*)d_in[1];
    const float* Wk = (const float*)d_in[2];
    const float* Wv = (const float*)d_in[3];
    const float* Wo = (const float*)d_in[4];
    float* out = (float*)d_out;

    const int M = BATCH * SEQ;          // 4096

    // ws layout (r19/r20): Abf bf16 [4096][1024] in the old XQKV slot.
    // WT bf16 [2048][1024] (AO32 aliases WT) | WoPt | Qp | Kb | Vtg.
    short* Abf  = (short*)d_ws;
    short* WT   = (short*)((float*)d_ws + (size_t)M * 2048);
    short* WoPt = WT + (size_t)2048 * 1024;
    short* Qp   = WoPt + (size_t)1024 * 512;
    short* Kb   = Qp + (size_t)M * 512;
    short* Vtg  = Kb + (size_t)M * 512;
    short* AO32 = WT;   // alias

    dim3 blk(256);

    // 1) Weight prep (sigma-permuted Q/K regions) + activation cvt
    prep_weights<<<dim3(32, 32, 6), blk, 0, stream>>>(Wq, Wk, Wv, Wo, WT, WoPt, q, Abf);

    // 2) QKV projection with fused in-lane rope/transpose epilogue
    gemm_qkv<<<dim3(16, 32), blk, 0, stream>>>(Abf, WT, Qp, Kb, Vtg);

    // 3) Flash attention (512 blocks x 512 threads) -> AO32 (aliases WT)
    flash_attn<<<BATCH * HEADS * (SEQ / 128), dim3(512), 0, stream>>>(Qp, Kb, Vtg, AO32);

    // 4) Output GEMM -> f32 out
    gemm_wo<<<dim3(8, 64), blk, 0, stream>>>(AO32, WoPt, out);
}